// Round 4
// baseline (241.923 us; speedup 1.0000x reference)
//
#include <hip/hip_runtime.h>
#include <math.h>

// idct_54271206752953: per 8x8 block, O = D^T * S * D + 128, D[x][u] = 0.5*a[x]*cos((2u+1)x*pi/16).
//
// R8 = R7 resubmitted verbatim (R7 bench was an infra failure: container
// acquisition failed twice; kernel never built/ran — nothing to revise).
//
// R7 = R6 with the compile fix: __builtin_nontemporal_store requires a clang
// native vector type (ext_vector_type), not HIP's float4 class. Loads/stores
// now go through `v4f` (float __attribute__((ext_vector_type(4)))).
//
// R5/R6 changes (register-pressure + epilogue micro-opts targeting the
// 64-VGPR / 8-waves-per-SIMD occupancy cliff):
//   - col[8] array deleted: the 7-op D-column select tree is folded into each
//     P2STEP right before use (8 fewer long-lived VGPRs; the tree's VALU ops
//     also overlap the previous step's ds_swizzle latency window).
//   - accumulator initialized at 128.0f -> no epilogue adds, stores issue
//     immediately after the last FMA.
//   - __launch_bounds__(256, 8) pins the allocator at <=64 VGPR (est. ~40).
//   - nontemporal stores: output is stream-out, nothing to keep in L2/L3.
// Shape unchanged: 8 lanes per block, row-per-lane, NO LDS alloc, NO barriers:
//   - lane u of each 8-lane group loads/stores row u (2 x 16B; wave covers
//     2KB contiguous both directions).
//   - pass 1 (S*D): lane-local, D from SGPRs (kernarg by value).
//   - pass 2 (D^T*T): ds_swizzle broadcast of lane x's row within the 8-group
//     (pattern (x<<5)|0x18: and=0x18 keeps group bits, or=x selects source).

typedef float v4f __attribute__((ext_vector_type(4)));  // clang-native vec4

struct DMat { float d[64]; };  // by value -> kernarg -> SGPRs

template <int PAT>
__device__ __forceinline__ float bcast8(float v) {
    return __int_as_float(__builtin_amdgcn_ds_swizzle(__float_as_int(v), PAT));
}

__global__ __launch_bounds__(256, 8) void idct8(
    const float* __restrict__ img, float* __restrict__ out, DMat dm, int nblk)
{
    const int tid = blockIdx.x * 256 + threadIdx.x;
    const int u = tid & 7;                  // row within block
    const size_t blk = (size_t)(tid >> 3);  // one block per 8 lanes
    if (blk >= (size_t)nblk) return;        // group-uniform guard

    // ---- load my row (32B, two 16B vectors; wave = 2KB contiguous) ----
    const float* ip = img + blk * 64 + u * 8;
    v4f a = *(const v4f*)ip;
    v4f b = *(const v4f*)(ip + 4);
    float s[8] = {a.x, a.y, a.z, a.w, b.x, b.y, b.z, b.w};

    const bool u1 = (u & 1), u2 = (u & 2), u4 = (u & 4);

    // ---- pass 1 (lane-local): t[v] = sum_y s[y] * D[y][v]  (D from SGPRs) ----
    float t[8];
#pragma unroll
    for (int v = 0; v < 8; ++v) {
        float acc = 0.0f;
#pragma unroll
        for (int y = 0; y < 8; ++y)
            acc = fmaf(s[y], dm.d[y * 8 + v], acc);
        t[v] = acc;
    }

    // ---- pass 2: o[v] = 128 + sum_x D[x][u] * t_lane_x[v], 8-group broadcast.
    // D column element D[X][u] built per step via select tree (no col[] array).
    float o[8] = {128.0f, 128.0f, 128.0f, 128.0f,
                  128.0f, 128.0f, 128.0f, 128.0f};
#define P2STEP(X)                                                         \
    {                                                                     \
        constexpr int pat = ((X) << 5) | 0x18;                            \
        float a01 = u1 ? dm.d[(X) * 8 + 1] : dm.d[(X) * 8 + 0];           \
        float a23 = u1 ? dm.d[(X) * 8 + 3] : dm.d[(X) * 8 + 2];           \
        float a45 = u1 ? dm.d[(X) * 8 + 5] : dm.d[(X) * 8 + 4];           \
        float a67 = u1 ? dm.d[(X) * 8 + 7] : dm.d[(X) * 8 + 6];           \
        float a03 = u2 ? a23 : a01;                                       \
        float a47 = u2 ? a67 : a45;                                       \
        float cx = u4 ? a47 : a03;                                        \
        _Pragma("unroll")                                                 \
        for (int v = 0; v < 8; ++v)                                       \
            o[v] = fmaf(cx, bcast8<pat>(t[v]), o[v]);                     \
    }
    P2STEP(0) P2STEP(1) P2STEP(2) P2STEP(3)
    P2STEP(4) P2STEP(5) P2STEP(6) P2STEP(7)
#undef P2STEP

    // ---- store my row (nontemporal: pure stream-out) ----
    float* op = out + blk * 64 + u * 8;
    v4f w0 = {o[0], o[1], o[2], o[3]};
    v4f w1 = {o[4], o[5], o[6], o[7]};
    __builtin_nontemporal_store(w0, (v4f*)op);
    __builtin_nontemporal_store(w1, (v4f*)(op + 4));
}

// Scalar tail (one thread per block) for nblk % 8 != 0 (unused at 524288).
__global__ __launch_bounds__(64) void idct_tail(
    const float* __restrict__ img, float* __restrict__ out, DMat dm,
    int first, int nblk)
{
    int m = first + blockIdx.x * 64 + threadIdx.x;
    if (m >= nblk) return;
    const float* ip = img + (size_t)m * 64;
    float s[64];
#pragma unroll
    for (int i = 0; i < 64; ++i) s[i] = ip[i];
#pragma unroll
    for (int x = 0; x < 8; ++x) {
        float tt[8];
#pragma unroll
        for (int v = 0; v < 8; ++v) {
            float acc = 0.0f;
#pragma unroll
            for (int y = 0; y < 8; ++y) acc = fmaf(s[x * 8 + y], dm.d[y * 8 + v], acc);
            tt[v] = acc;
        }
#pragma unroll
        for (int v = 0; v < 8; ++v) s[x * 8 + v] = tt[v];
    }
    float* opf = out + (size_t)m * 64;
#pragma unroll
    for (int v = 0; v < 8; ++v) {
        float c[8];
#pragma unroll
        for (int x = 0; x < 8; ++x) c[x] = s[x * 8 + v];
#pragma unroll
        for (int u = 0; u < 8; ++u) {
            float acc = 0.0f;
#pragma unroll
            for (int x = 0; x < 8; ++x) acc = fmaf(c[x], dm.d[x * 8 + u], acc);
            opf[u * 8 + v] = acc + 128.0f;
        }
    }
}

extern "C" void kernel_launch(void* const* d_in, const int* in_sizes, int n_in,
                              void* d_out, int out_size, void* d_ws, size_t ws_size,
                              hipStream_t stream) {
    const float* img = (const float*)d_in[0];
    float* out = (float*)d_out;
    int nblk = in_sizes[0] / 64;  // 524288

    DMat dm;
    const double PI = 3.14159265358979323846;
    for (int x = 0; x < 8; ++x) {
        double ax = (x == 0) ? (1.0 / sqrt(2.0)) : 1.0;
        for (int u = 0; u < 8; ++u)
            dm.d[x * 8 + u] = (float)(0.5 * ax * cos((2 * u + 1) * x * PI / 16.0));
    }

    int nMain = nblk & ~7;                 // blocks handled by idct8 (whole 8-groups)
    if (nMain > 0) {
        int threads = nMain * 8;           // 8 lanes per block
        int nwg = (threads + 255) / 256;
        idct8<<<nwg, 256, 0, stream>>>(img, out, dm, nMain);
    }
    int rem = nblk - nMain;
    if (rem > 0)
        idct_tail<<<(rem + 63) / 64, 64, 0, stream>>>(img, out, dm, nMain, nblk);
}